// Round 2
// baseline (778.953 us; speedup 1.0000x reference)
//
#include <hip/hip_runtime.h>
#include <hip/hip_bf16.h>
#include <math.h>

typedef __bf16 bf16_t;
typedef __bf16 bf16x4_t __attribute__((ext_vector_type(4)));
typedef __bf16 bf16x8_t __attribute__((ext_vector_type(8)));
typedef float  f32x4    __attribute__((ext_vector_type(4)));

#define NE  8
#define NR  16
#define ND  2048
#define NH  8192
#define NT  4096
#define NER 128              // NE*NR
#define NK1 (ND + NER)       // 2176
#define NK2 (NH + NER)       // 8320

// gelu_new via sigmoid: 0.5x(1+tanh(u)) == x * sigmoid(2u)
static __device__ __forceinline__ float gelu_fast(float x) {
    const float c2 = 1.5957691216057308f;  // 2*sqrt(2/pi)
    float u2 = c2 * (x + 0.044715f * x * x * x);
    return x / (1.0f + __expf(-u2));
}

// async global->LDS, 16B per lane; LDS dest is wave-uniform base + lane*16
static __device__ __forceinline__ void load16_to_lds(const bf16_t* g, bf16_t* l) {
    __builtin_amdgcn_global_load_lds(
        (__attribute__((address_space(1))) void*)(g),
        (__attribute__((address_space(3))) void*)(l),
        16, 0, 0);
}

// ---------------------------------------------------------------------------
// x fp32 -> Xaug1[:, 0:ND] bf16
// ---------------------------------------------------------------------------
__global__ __launch_bounds__(256) void conv_x(
    const float* __restrict__ x, bf16_t* __restrict__ Xa1)
{
    const int i  = blockIdx.x * 256 + threadIdx.x;   // < NT*ND/4
    const int row = i >> 9;                          // ND/4 = 512
    const int c4  = i & 511;
    f32x4 v = *(const f32x4*)(x + (long)i * 4);
    bf16x4_t o = {(bf16_t)v[0], (bf16_t)v[1], (bf16_t)v[2], (bf16_t)v[3]};
    *(bf16x4_t*)(Xa1 + (long)row * NK1 + (c4 << 2)) = o;
}

// ---------------------------------------------------------------------------
// fp32 [nrows][K0] -> bf16 [nrows][ld] (dst cols 0..K0)
// ---------------------------------------------------------------------------
__global__ __launch_bounds__(256) void prep_main(
    const float* __restrict__ W, bf16_t* __restrict__ Waug,
    int ld, int shift, int total4)
{
    const int i = blockIdx.x * 256 + threadIdx.x;
    if (i >= total4) return;
    const int row = i >> shift;
    const int c4  = i & ((1 << shift) - 1);
    f32x4 v = *(const f32x4*)(W + (long)i * 4);
    bf16x4_t o = {(bf16_t)v[0], (bf16_t)v[1], (bf16_t)v[2], (bf16_t)v[3]};
    *(bf16x4_t*)(Waug + (long)row * ld + (c4 << 2)) = o;
}

// lora region: Waug[row][K0 + e*16 + r] = Blora[e][row][r]
__global__ __launch_bounds__(256) void prep_lora(
    const float* __restrict__ Bl, bf16_t* __restrict__ Waug,
    int nrows, int K0, int ld, int total)
{
    const int i = blockIdx.x * 256 + threadIdx.x;
    if (i >= total) return;
    const int row = i >> 7;
    const int c   = i & 127;
    const int e   = c >> 4;
    const int r   = c & 15;
    float v = Bl[((long)e * nrows + row) * NR + r];
    Waug[(long)row * ld + K0 + c] = (bf16_t)v;
}

// ---------------------------------------------------------------------------
// bf16 GEMM: C[m][n] = sum_k A[m][k]*Bt[n][k]
// 128x128 tile, BK=32, 4 waves 2x2, 16x16x32 MFMA, global_load_lds w=16.
// MODE 0: +bias, gelu -> bf16 (coalesced via LDS repack)
// MODE 1: +bias -> fp32 direct store
// MODE 2: expert-mask * 2 -> bf16 (LDS repack); Cout pre-offset to lora cols
// ---------------------------------------------------------------------------
template <int K, int LDA, int LDB, int LDC, int MODE>
__global__ __launch_bounds__(256) void gemm_bt(
    const bf16_t* __restrict__ A,  const bf16_t* __restrict__ Bt,
    const float* __restrict__ bias, const int* __restrict__ eidx,
    void* __restrict__ Cout)
{
    __shared__ union {
        struct { bf16_t As[128 * 32]; bf16_t Bs[128 * 32]; } s;
        bf16_t Cs[64 * 136];
    } u;

    const int tid   = threadIdx.x;
    const int wave  = tid >> 6;
    const int lane  = tid & 63;
    const int col16 = lane & 15;
    const int q     = lane >> 4;
    const int wm    = wave & 1;
    const int wn    = wave >> 1;

    const int rowA0 = blockIdx.y * 128;
    const int colB0 = blockIdx.x * 128;

    // staging: one global_load_lds = 64 lanes x 16B = 16 rows x 32-k
    const int srow  = lane >> 2;
    const int skoff = (lane & 3) * 8;
    const int r0a = wave * 32;
    const int r0b = wave * 32 + 16;

    const bf16_t* Ag0 = A  + (long)(rowA0 + r0a + srow) * LDA + skoff;
    const bf16_t* Ag1 = A  + (long)(rowA0 + r0b + srow) * LDA + skoff;
    const bf16_t* Bg0 = Bt + (long)(colB0 + r0a + srow) * LDB + skoff;
    const bf16_t* Bg1 = Bt + (long)(colB0 + r0b + srow) * LDB + skoff;
    bf16_t* AsD0 = &u.s.As[r0a * 32];
    bf16_t* AsD1 = &u.s.As[r0b * 32];
    bf16_t* BsD0 = &u.s.Bs[r0a * 32];
    bf16_t* BsD1 = &u.s.Bs[r0b * 32];

    // loop-invariant LDS read bases
    const bf16_t* Ard = &u.s.As[(wm * 64 + col16) * 32 + q * 8];
    const bf16_t* Brd = &u.s.Bs[(wn * 64 + col16) * 32 + q * 8];

    f32x4 acc[4][4];
#pragma unroll
    for (int i = 0; i < 4; ++i)
#pragma unroll
        for (int j = 0; j < 4; ++j)
            acc[i][j] = (f32x4){0.f, 0.f, 0.f, 0.f};

#pragma unroll 2
    for (int it = 0; it < K / 32; ++it) {
        load16_to_lds(Ag0, AsD0); Ag0 += 32;
        load16_to_lds(Ag1, AsD1); Ag1 += 32;
        load16_to_lds(Bg0, BsD0); Bg0 += 32;
        load16_to_lds(Bg1, BsD1); Bg1 += 32;
        __syncthreads();

        bf16x8_t af[4], bfr[4];
#pragma unroll
        for (int mt = 0; mt < 4; ++mt)
            af[mt] = *(const bf16x8_t*)(Ard + mt * 16 * 32);
#pragma unroll
        for (int nt = 0; nt < 4; ++nt)
            bfr[nt] = *(const bf16x8_t*)(Brd + nt * 16 * 32);

#pragma unroll
        for (int mt = 0; mt < 4; ++mt)
#pragma unroll
            for (int nt = 0; nt < 4; ++nt)
                acc[mt][nt] = __builtin_amdgcn_mfma_f32_16x16x32_bf16(
                    af[mt], bfr[nt], acc[mt][nt], 0, 0, 0);

        __syncthreads();
    }

    if (MODE == 1) {
        // fp32 direct store (4B/lane coalesced)
        float* Cf = (float*)Cout;
#pragma unroll
        for (int nt = 0; nt < 4; ++nt) {
            const int col = colB0 + wn * 64 + nt * 16 + col16;
            const float bv = bias[col];
#pragma unroll
            for (int mt = 0; mt < 4; ++mt) {
                const int row0 = rowA0 + wm * 64 + mt * 16 + q * 4;
#pragma unroll
                for (int i = 0; i < 4; ++i)
                    Cf[(long)(row0 + i) * LDC + col] = acc[mt][nt][i] + bv;
            }
        }
    } else {
        // bf16 output via LDS repack: two 64-row halves, coalesced 16B stores
        bf16_t* Cb = (bf16_t*)Cout;
#pragma unroll
        for (int half = 0; half < 2; ++half) {
            if (wm == half) {
#pragma unroll
                for (int nt = 0; nt < 4; ++nt) {
                    const int c = wn * 64 + nt * 16 + col16;
                    const float bv = (MODE == 0) ? bias[colB0 + c] : 0.0f;
#pragma unroll
                    for (int mt = 0; mt < 4; ++mt) {
                        const int rl = mt * 16 + q * 4;        // row in half
                        const int t  = rowA0 + half * 64 + rl; // global row
#pragma unroll
                        for (int i = 0; i < 4; ++i) {
                            float v = acc[mt][nt][i];
                            if (MODE == 0) {
                                v = gelu_fast(v + bv);
                            } else {
                                const int e = eidx[t + i];
                                v = (e == (c >> 4)) ? 2.0f * v : 0.0f;
                            }
                            u.Cs[(rl + i) * 136 + c] = (bf16_t)v;
                        }
                    }
                }
            }
            __syncthreads();
            {
                const int r  = tid >> 2;          // 0..63
                const int c0 = (tid & 3) * 32;    // 0,32,64,96
                const long gbase =
                    (long)(rowA0 + half * 64 + r) * LDC + colB0 + c0;
#pragma unroll
                for (int ch = 0; ch < 4; ++ch) {
                    bf16x8_t v = *(const bf16x8_t*)&u.Cs[r * 136 + c0 + ch * 8];
                    *(bf16x8_t*)&Cb[gbase + ch * 8] = v;
                }
            }
            __syncthreads();
        }
    }
}

// ---------------------------------------------------------------------------
extern "C" void kernel_launch(void* const* d_in, const int* in_sizes, int n_in,
                              void* d_out, int out_size, void* d_ws, size_t ws_size,
                              hipStream_t stream)
{
    const float* x    = (const float*)d_in[0];
    const int*   eidx = (const int*)  d_in[1];
    const float* W1   = (const float*)d_in[2];
    const float* b1   = (const float*)d_in[3];
    const float* A1   = (const float*)d_in[4];
    const float* B1   = (const float*)d_in[5];
    const float* W2   = (const float*)d_in[6];
    const float* b2   = (const float*)d_in[7];
    const float* A2   = (const float*)d_in[8];
    const float* B2   = (const float*)d_in[9];
    float* out = (float*)d_out;

    // workspace carve (bytes), peak 121,634,816 (same as R1):
    //   Xaug2 : [0, 68,157,440)
    //   Xaug1 : [68,157,440, 85,983,232)   dead after GEMM1
    //   W1aug : [85,983,232, 121,634,816)  dead after GEMM1
    //   W2aug : [68,157,440, 102,236,160)  written after GEMM1 (aliases above)
    //   A1b   : [104,000,000, +512K)   used before W1aug prep clobbers it
    //   A2b   : [104,857,600, +2M)     written after GEMM1, inside dead W1aug
    char* ws = (char*)d_ws;
    bf16_t* Xaug2 = (bf16_t*)(ws);
    bf16_t* Xaug1 = (bf16_t*)(ws + 68157440L);
    bf16_t* W1aug = (bf16_t*)(ws + 85983232L);
    bf16_t* W2aug = (bf16_t*)(ws + 68157440L);
    bf16_t* A1b   = (bf16_t*)(ws + 104000000L);
    bf16_t* A2b   = (bf16_t*)(ws + 104857600L);

    // --- layer 1 ---
    conv_x<<<NT * ND / 4 / 256, 256, 0, stream>>>(x, Xaug1);
    prep_main<<<(NER * ND / 4) / 256, 256, 0, stream>>>(A1, A1b, ND, 9, NER * ND / 4);
    {   // LoRA1: z = 2*mask(x @ A1^T) -> Xaug1[:, ND:ND+128]
        dim3 g(1, NT / 128);
        gemm_bt<ND, NK1, ND, NK1, 2><<<g, 256, 0, stream>>>(
            Xaug1, A1b, nullptr, eidx, (void*)(Xaug1 + ND));
    }
    prep_main<<<(NH * ND / 4) / 256, 256, 0, stream>>>(W1, W1aug, NK1, 9, NH * ND / 4);
    prep_lora<<<(NH * NER) / 256, 256, 0, stream>>>(B1, W1aug, NH, ND, NK1, NH * NER);
    {   // GEMM1: y = gelu(Xaug1 @ W1aug^T + b1) -> Xaug2[:, 0:NH] bf16
        dim3 g(NH / 128, NT / 128);
        gemm_bt<NK1, NK1, NK1, NK2, 0><<<g, 256, 0, stream>>>(
            Xaug1, W1aug, b1, nullptr, (void*)Xaug2);
    }

    // --- layer 2 ---
    prep_main<<<(NER * NH / 4) / 256, 256, 0, stream>>>(A2, A2b, NH, 11, NER * NH / 4);
    {   // LoRA2: z = 2*mask(y @ A2^T) -> Xaug2[:, NH:NH+128]
        dim3 g(1, NT / 128);
        gemm_bt<NH, NK2, NH, NK2, 2><<<g, 256, 0, stream>>>(
            Xaug2, A2b, nullptr, eidx, (void*)(Xaug2 + NH));
    }
    prep_main<<<(ND * NH / 4) / 256, 256, 0, stream>>>(W2, W2aug, NK2, 11, ND * NH / 4);
    prep_lora<<<(ND * NER) / 256, 256, 0, stream>>>(B2, W2aug, ND, NH, NK2, ND * NER);
    {   // GEMM2: out = Xaug2 @ W2aug^T + b2 (fp32)
        dim3 g(ND / 128, NT / 128);
        gemm_bt<NK2, NK2, NK2, ND, 1><<<g, 256, 0, stream>>>(
            Xaug2, W2aug, b2, nullptr, (void*)out);
    }
}

// Round 3
// 657.966 us; speedup vs baseline: 1.1839x; 1.1839x over previous
//
#include <hip/hip_runtime.h>
#include <hip/hip_bf16.h>
#include <math.h>

typedef __bf16 bf16_t;
typedef __bf16 bf16x4_t __attribute__((ext_vector_type(4)));
typedef __bf16 bf16x8_t __attribute__((ext_vector_type(8)));
typedef float  f32x4    __attribute__((ext_vector_type(4)));

#define NE  8
#define NR  16
#define ND  2048
#define NH  8192
#define NT  4096
#define NER 128              // NE*NR
#define NK1 (ND + NER)       // 2176
#define NK2 (NH + NER)       // 8320

// gelu_new via sigmoid: 0.5x(1+tanh(u)) == x * sigmoid(2u)
static __device__ __forceinline__ float gelu_fast(float x) {
    const float c2 = 1.5957691216057308f;  // 2*sqrt(2/pi)
    float u2 = c2 * (x + 0.044715f * x * x * x);
    return x / (1.0f + __expf(-u2));
}

// async global->LDS, 16B per lane; LDS dest = wave-uniform base + lane*16
static __device__ __forceinline__ void load16_to_lds(const bf16_t* g, bf16_t* l) {
    __builtin_amdgcn_global_load_lds(
        (__attribute__((address_space(1))) void*)(g),
        (__attribute__((address_space(3))) void*)(l),
        16, 0, 0);
}

// ---------------------------------------------------------------------------
// x fp32 -> Xaug1[:, 0:ND] bf16
// ---------------------------------------------------------------------------
__global__ __launch_bounds__(256) void conv_x(
    const float* __restrict__ x, bf16_t* __restrict__ Xa1)
{
    const int i  = blockIdx.x * 256 + threadIdx.x;   // < NT*ND/4
    const int row = i >> 9;
    const int c4  = i & 511;
    f32x4 v = *(const f32x4*)(x + (long)i * 4);
    bf16x4_t o = {(bf16_t)v[0], (bf16_t)v[1], (bf16_t)v[2], (bf16_t)v[3]};
    *(bf16x4_t*)(Xa1 + (long)row * NK1 + (c4 << 2)) = o;
}

// fp32 [nrows][K0] -> bf16 [nrows][ld] (dst cols 0..K0)
__global__ __launch_bounds__(256) void prep_main(
    const float* __restrict__ W, bf16_t* __restrict__ Waug,
    int ld, int shift, int total4)
{
    const int i = blockIdx.x * 256 + threadIdx.x;
    if (i >= total4) return;
    const int row = i >> shift;
    const int c4  = i & ((1 << shift) - 1);
    f32x4 v = *(const f32x4*)(W + (long)i * 4);
    bf16x4_t o = {(bf16_t)v[0], (bf16_t)v[1], (bf16_t)v[2], (bf16_t)v[3]};
    *(bf16x4_t*)(Waug + (long)row * ld + (c4 << 2)) = o;
}

// lora region: Waug[row][K0 + e*16 + r] = Blora[e][row][r]
__global__ __launch_bounds__(256) void prep_lora(
    const float* __restrict__ Bl, bf16_t* __restrict__ Waug,
    int nrows, int K0, int ld, int total)
{
    const int i = blockIdx.x * 256 + threadIdx.x;
    if (i >= total) return;
    const int row = i >> 7;
    const int c   = i & 127;
    const int e   = c >> 4;
    const int r   = c & 15;
    float v = Bl[((long)e * nrows + row) * NR + r];
    Waug[(long)row * ld + K0 + c] = (bf16_t)v;
}

// split-K reduce for LoRA: sum partials, expert-mask, *2, -> bf16 lora cols
template <int SPLITS, int LD>
__global__ __launch_bounds__(256) void zred(
    const float* __restrict__ zp, const int* __restrict__ eidx,
    bf16_t* __restrict__ dst)
{
    const int i = blockIdx.x * 256 + threadIdx.x;  // < NT*128
    const int t = i >> 7;
    const int c = i & 127;
    float s = 0.f;
#pragma unroll
    for (int j = 0; j < SPLITS; ++j) s += zp[(long)j * NT * 128 + i];
    const int e = eidx[t];
    float v = ((c >> 4) == e) ? 2.0f * s : 0.f;
    dst[(long)t * LD + c] = (bf16_t)v;
}

// ---------------------------------------------------------------------------
// bf16 GEMM: C[m][n] = sum_k A[m][k]*Bt[n][k]
// 128x128 tile, BK=64 (32 MFMA/wave between barriers), 4 waves 2x2,
// 16x16x32 MFMA, global_load_lds width=16.
// MODE 0: +bias, gelu -> bf16 (coalesced via LDS repack)
// MODE 1: +bias -> fp32 direct store
// MODE 3: split-K partial: blockIdx.x = k-chunk, colB0=0, fp32 -> zp[chunk]
// ---------------------------------------------------------------------------
template <int K, int LDA, int LDB, int LDC, int MODE>
__global__ __launch_bounds__(256) void gemm_bt(
    const bf16_t* __restrict__ A,  const bf16_t* __restrict__ Bt,
    const float* __restrict__ bias, void* __restrict__ Cout)
{
    __shared__ union {
        struct { bf16_t As[128 * 64]; bf16_t Bs[128 * 64]; } s;  // 32 KB
        bf16_t Cs[64 * 136];
    } u;

    const int tid   = threadIdx.x;
    const int wave  = tid >> 6;
    const int lane  = tid & 63;
    const int col16 = lane & 15;
    const int q     = lane >> 4;
    const int wm    = wave & 1;
    const int wn    = wave >> 1;

    const int  rowA0 = blockIdx.y * 128;
    const int  colB0 = (MODE == 3) ? 0 : blockIdx.x * 128;
    const long koff  = (MODE == 3) ? (long)blockIdx.x * K : 0;

    // staging: one global_load_lds = 64 lanes x 16B = 8 rows x 64-k
    const int srow  = lane >> 3;        // 0..7
    const int skoff = (lane & 7) * 8;   // element offset within row

    const bf16_t* Ag = A  + (long)(rowA0 + wave * 32 + srow) * LDA + koff + skoff;
    const bf16_t* Bg = Bt + (long)(colB0 + wave * 32 + srow) * LDB + koff + skoff;
    bf16_t* AsD = &u.s.As[wave * 32 * 64];
    bf16_t* BsD = &u.s.Bs[wave * 32 * 64];

    const bf16_t* Ard = &u.s.As[(wm * 64 + col16) * 64 + q * 8];
    const bf16_t* Brd = &u.s.Bs[(wn * 64 + col16) * 64 + q * 8];

    f32x4 acc[4][4];
#pragma unroll
    for (int i = 0; i < 4; ++i)
#pragma unroll
        for (int j = 0; j < 4; ++j)
            acc[i][j] = (f32x4){0.f, 0.f, 0.f, 0.f};

    for (int it = 0; it < K / 64; ++it) {
#pragma unroll
        for (int j = 0; j < 4; ++j) {
            load16_to_lds(Ag + (long)(j * 8) * LDA, AsD + j * 8 * 64);
            load16_to_lds(Bg + (long)(j * 8) * LDB, BsD + j * 8 * 64);
        }
        Ag += 64; Bg += 64;
        __syncthreads();

#pragma unroll
        for (int h = 0; h < 2; ++h) {
            bf16x8_t af[4], bfr[4];
#pragma unroll
            for (int mt = 0; mt < 4; ++mt)
                af[mt] = *(const bf16x8_t*)(Ard + mt * 16 * 64 + h * 32);
#pragma unroll
            for (int nt = 0; nt < 4; ++nt)
                bfr[nt] = *(const bf16x8_t*)(Brd + nt * 16 * 64 + h * 32);
#pragma unroll
            for (int mt = 0; mt < 4; ++mt)
#pragma unroll
                for (int nt = 0; nt < 4; ++nt)
                    acc[mt][nt] = __builtin_amdgcn_mfma_f32_16x16x32_bf16(
                        af[mt], bfr[nt], acc[mt][nt], 0, 0, 0);
        }
        __syncthreads();
    }

    if (MODE == 1) {
        float* Cf = (float*)Cout;
#pragma unroll
        for (int nt = 0; nt < 4; ++nt) {
            const int col = colB0 + wn * 64 + nt * 16 + col16;
            const float bv = bias[col];
#pragma unroll
            for (int mt = 0; mt < 4; ++mt) {
                const int row0 = rowA0 + wm * 64 + mt * 16 + q * 4;
#pragma unroll
                for (int i = 0; i < 4; ++i)
                    Cf[(long)(row0 + i) * LDC + col] = acc[mt][nt][i] + bv;
            }
        }
    } else if (MODE == 3) {
        float* Cf = (float*)Cout + (long)blockIdx.x * NT * LDC;
#pragma unroll
        for (int nt = 0; nt < 4; ++nt) {
            const int col = wn * 64 + nt * 16 + col16;
#pragma unroll
            for (int mt = 0; mt < 4; ++mt) {
                const int row0 = rowA0 + wm * 64 + mt * 16 + q * 4;
#pragma unroll
                for (int i = 0; i < 4; ++i)
                    Cf[(long)(row0 + i) * LDC + col] = acc[mt][nt][i];
            }
        }
    } else {
        // MODE 0: bf16 output via LDS repack, coalesced 16B stores
        bf16_t* Cb = (bf16_t*)Cout;
#pragma unroll
        for (int half = 0; half < 2; ++half) {
            if (wm == half) {
#pragma unroll
                for (int nt = 0; nt < 4; ++nt) {
                    const int c = wn * 64 + nt * 16 + col16;
                    const float bv = bias[colB0 + c];
#pragma unroll
                    for (int mt = 0; mt < 4; ++mt) {
                        const int rl = mt * 16 + q * 4;
#pragma unroll
                        for (int i = 0; i < 4; ++i)
                            u.Cs[(rl + i) * 136 + c] =
                                (bf16_t)gelu_fast(acc[mt][nt][i] + bv);
                    }
                }
            }
            __syncthreads();
            {
                const int r  = tid >> 2;
                const int c0 = (tid & 3) * 32;
                const long gbase =
                    (long)(rowA0 + half * 64 + r) * LDC + colB0 + c0;
#pragma unroll
                for (int ch = 0; ch < 4; ++ch) {
                    bf16x8_t v = *(const bf16x8_t*)&u.Cs[r * 136 + c0 + ch * 8];
                    *(bf16x8_t*)&Cb[gbase + ch * 8] = v;
                }
            }
            __syncthreads();
        }
    }
}

// ---------------------------------------------------------------------------
extern "C" void kernel_launch(void* const* d_in, const int* in_sizes, int n_in,
                              void* d_out, int out_size, void* d_ws, size_t ws_size,
                              hipStream_t stream)
{
    const float* x    = (const float*)d_in[0];
    const int*   eidx = (const int*)  d_in[1];
    const float* W1   = (const float*)d_in[2];
    const float* b1   = (const float*)d_in[3];
    const float* A1   = (const float*)d_in[4];
    const float* B1   = (const float*)d_in[5];
    const float* W2   = (const float*)d_in[6];
    const float* b2   = (const float*)d_in[7];
    const float* A2   = (const float*)d_in[8];
    const float* B2   = (const float*)d_in[9];
    float* out = (float*)d_out;

    // workspace carve (bytes), peak 121,634,816:
    //   Xaug2 : [0, 68,157,440)                        live whole pass
    //   Xaug1 : [68,157,440, 85,983,232)               dead after GEMM1
    //   W1aug : [85,983,232, 121,634,816)              dead after GEMM1
    //   A1b   : 104,000,000 +512K   (inside W1aug region, used pre-W1aug-prep)
    //   zp1   : 106,954,752 +8M     (ditto)
    //   W2aug : [68,157,440, 102,236,160)              written after zred2
    //   zp2   : [85,983,232, 102,760,448)              used pre-W2aug-prep
    //   A2b   : 104,857,600 +2M     (outside W2aug, used after GEMM1)
    char* ws = (char*)d_ws;
    bf16_t* Xaug2 = (bf16_t*)(ws);
    bf16_t* Xaug1 = (bf16_t*)(ws + 68157440L);
    bf16_t* W1aug = (bf16_t*)(ws + 85983232L);
    bf16_t* W2aug = (bf16_t*)(ws + 68157440L);
    bf16_t* A1b   = (bf16_t*)(ws + 104000000L);
    bf16_t* A2b   = (bf16_t*)(ws + 104857600L);
    float*  zp1   = (float*) (ws + 106954752L);
    float*  zp2   = (float*) (ws + 85983232L);

    // --- layer 1 ---
    conv_x<<<NT * ND / 4 / 256, 256, 0, stream>>>(x, Xaug1);
    prep_main<<<(NER * ND / 4) / 256, 256, 0, stream>>>(A1, A1b, ND, 9, NER * ND / 4);
    {   // LoRA1 split-K: 4 chunks x K=512, grid 128 blocks
        dim3 g(4, NT / 128);
        gemm_bt<512, NK1, ND, 128, 3><<<g, 256, 0, stream>>>(
            Xaug1, A1b, nullptr, (void*)zp1);
    }
    zred<4, NK1><<<NT * 128 / 256, 256, 0, stream>>>(zp1, eidx, Xaug1 + ND);
    prep_main<<<(NH * ND / 4) / 256, 256, 0, stream>>>(W1, W1aug, NK1, 9, NH * ND / 4);
    prep_lora<<<(NH * NER) / 256, 256, 0, stream>>>(B1, W1aug, NH, ND, NK1, NH * NER);
    {   // GEMM1: y = gelu(Xaug1 @ W1aug^T + b1) -> Xaug2[:, 0:NH] bf16
        dim3 g(NH / 128, NT / 128);
        gemm_bt<NK1, NK1, NK1, NK2, 0><<<g, 256, 0, stream>>>(
            Xaug1, W1aug, b1, (void*)Xaug2);
    }

    // --- layer 2 ---
    prep_main<<<(NER * NH / 4) / 256, 256, 0, stream>>>(A2, A2b, NH, 11, NER * NH / 4);
    {   // LoRA2 split-K: 8 chunks x K=1024, grid 256 blocks
        dim3 g(8, NT / 128);
        gemm_bt<1024, NK2, NH, 128, 3><<<g, 256, 0, stream>>>(
            Xaug2, A2b, nullptr, (void*)zp2);
    }
    zred<8, NK2><<<NT * 128 / 256, 256, 0, stream>>>(zp2, eidx, Xaug2 + NH);
    prep_main<<<(ND * NH / 4) / 256, 256, 0, stream>>>(W2, W2aug, NK2, 11, ND * NH / 4);
    prep_lora<<<(ND * NER) / 256, 256, 0, stream>>>(B2, W2aug, ND, NH, NK2, ND * NER);
    {   // GEMM2: out = Xaug2 @ W2aug^T + b2 (fp32)
        dim3 g(ND / 128, NT / 128);
        gemm_bt<NK2, NK2, NK2, ND, 1><<<g, 256, 0, stream>>>(
            Xaug2, W2aug, b2, (void*)out);
    }
}

// Round 4
// 615.940 us; speedup vs baseline: 1.2647x; 1.0682x over previous
//
#include <hip/hip_runtime.h>
#include <hip/hip_bf16.h>
#include <math.h>

typedef __bf16 bf16_t;
typedef __bf16 bf16x4_t __attribute__((ext_vector_type(4)));
typedef __bf16 bf16x8_t __attribute__((ext_vector_type(8)));
typedef float  f32x4    __attribute__((ext_vector_type(4)));

#define NE  8
#define NR  16
#define ND  2048
#define NH  8192
#define NT  4096
#define NER 128              // NE*NR
#define NK1 (ND + NER)       // 2176
#define NK2 (NH + NER)       // 8320

// gelu_new via sigmoid: 0.5x(1+tanh(u)) == x * sigmoid(2u)
static __device__ __forceinline__ float gelu_fast(float x) {
    const float c2 = 1.5957691216057308f;  // 2*sqrt(2/pi)
    float u2 = c2 * (x + 0.044715f * x * x * x);
    return x / (1.0f + __expf(-u2));
}

static __device__ __forceinline__ void load16_to_lds(const bf16_t* g, bf16_t* l) {
    __builtin_amdgcn_global_load_lds(
        (__attribute__((address_space(1))) void*)(g),
        (__attribute__((address_space(3))) void*)(l),
        16, 0, 0);
}

// ---------------------------------------------------------------------------
// x fp32 -> Xaug1[:, 0:ND] bf16  (8 elems/thread)
// ---------------------------------------------------------------------------
__global__ __launch_bounds__(256) void conv_x(
    const float* __restrict__ x, bf16_t* __restrict__ Xa1)
{
    const int i  = blockIdx.x * 256 + threadIdx.x;   // < NT*ND/8
    const int row = i >> 8;                          // ND/8 = 256
    const int c8  = i & 255;
    f32x4 v0 = *(const f32x4*)(x + (long)i * 8);
    f32x4 v1 = *(const f32x4*)(x + (long)i * 8 + 4);
    bf16x8_t o = {(bf16_t)v0[0], (bf16_t)v0[1], (bf16_t)v0[2], (bf16_t)v0[3],
                  (bf16_t)v1[0], (bf16_t)v1[1], (bf16_t)v1[2], (bf16_t)v1[3]};
    *(bf16x8_t*)(Xa1 + (long)row * NK1 + (c8 << 3)) = o;
}

// fp32 [nrows][K0] -> bf16 [nrows][ld], 8 elems/thread; shift8 = log2(K0/8)
__global__ __launch_bounds__(256) void prep_main(
    const float* __restrict__ W, bf16_t* __restrict__ Waug,
    int ld, int shift8, int total8)
{
    const int i = blockIdx.x * 256 + threadIdx.x;
    if (i >= total8) return;
    const int row = i >> shift8;
    const int c8  = i & ((1 << shift8) - 1);
    f32x4 v0 = *(const f32x4*)(W + (long)i * 8);
    f32x4 v1 = *(const f32x4*)(W + (long)i * 8 + 4);
    bf16x8_t o = {(bf16_t)v0[0], (bf16_t)v0[1], (bf16_t)v0[2], (bf16_t)v0[3],
                  (bf16_t)v1[0], (bf16_t)v1[1], (bf16_t)v1[2], (bf16_t)v1[3]};
    *(bf16x8_t*)(Waug + (long)row * ld + (c8 << 3)) = o;
}

// lora region: Waug[row][K0 + e*16 + r] = Blora[e][row][r]
__global__ __launch_bounds__(256) void prep_lora(
    const float* __restrict__ Bl, bf16_t* __restrict__ Waug,
    int nrows, int K0, int ld, int total)
{
    const int i = blockIdx.x * 256 + threadIdx.x;
    if (i >= total) return;
    const int row = i >> 7;
    const int c   = i & 127;
    const int e   = c >> 4;
    const int r   = c & 15;
    float v = Bl[((long)e * nrows + row) * NR + r];
    Waug[(long)row * ld + K0 + c] = (bf16_t)v;
}

// split-K reduce for LoRA: sum partials, expert-mask, *2, -> bf16 lora cols
template <int SPLITS, int LD>
__global__ __launch_bounds__(256) void zred(
    const float* __restrict__ zp, const int* __restrict__ eidx,
    bf16_t* __restrict__ dst)
{
    const int i = blockIdx.x * 256 + threadIdx.x;  // < NT*128
    const int t = i >> 7;
    const int c = i & 127;
    float s = 0.f;
#pragma unroll
    for (int j = 0; j < SPLITS; ++j) s += zp[(long)j * NT * 128 + i];
    const int e = eidx[t];
    float v = ((c >> 4) == e) ? 2.0f * s : 0.f;
    dst[(long)t * LD + c] = (bf16_t)v;
}

// ---------------------------------------------------------------------------
// bf16 GEMM: C[m][n] = sum_k A[m][k]*Bt[n][k]
// 128x128 tile, BK=64 staged as two K=32 half-buffers (row stride 64 B ->
// 2-way-free LDS banking), 4 waves 2x2, 16x16x32 MFMA, global_load_lds w=16.
// Supertile swizzle (8 rows, col-major in group) for L2 locality (MODE 0/1).
// MODE 0: +bias, gelu -> bf16 (coalesced via LDS repack)
// MODE 1: +bias -> fp32 direct store
// MODE 3: split-K partial: blockIdx.x = k-chunk, colB0=0, fp32 -> zp[chunk]
// ---------------------------------------------------------------------------
template <int K, int LDA, int LDB, int LDC, int MODE, int GX>
__global__ __launch_bounds__(256) void gemm_bt(
    const bf16_t* __restrict__ A,  const bf16_t* __restrict__ Bt,
    const float* __restrict__ bias, void* __restrict__ Cout)
{
    __shared__ union {
        struct { bf16_t As[2 * 128 * 32]; bf16_t Bs[2 * 128 * 32]; } s; // 32 KB
        bf16_t Cs[64 * 136];
    } u;

    const int tid   = threadIdx.x;
    const int wave  = tid >> 6;
    const int lane  = tid & 63;
    const int col16 = lane & 15;
    const int q     = lane >> 4;
    const int wm    = wave & 1;
    const int wn    = wave >> 1;

    int rowA0, colB0;
    long koff = 0;
    if (MODE == 3) {
        rowA0 = blockIdx.y * 128;
        colB0 = 0;
        koff  = (long)blockIdx.x * K;
    } else {
        // supertile swizzle: groups of 8 row-strips, col-major within group
        const int lin = blockIdx.y * GX + blockIdx.x;
        const int PG  = 8 * GX;                 // power of 2
        const int gid = lin / PG;
        const int pm  = (gid << 3) + (lin & 7);
        const int pn  = (lin & (PG - 1)) >> 3;
        rowA0 = pm * 128;
        colB0 = pn * 128;
    }

    // staging: one global_load_lds = 64 lanes x 16B = 16 rows x 32-k (half)
    const int srow  = lane >> 2;        // 0..15
    const int skoff = (lane & 3) * 8;   // k offset within 32-half

    const bf16_t* Ag = A  + (long)(rowA0 + wave * 32 + srow) * LDA + koff + skoff;
    const bf16_t* Bg = Bt + (long)(colB0 + wave * 32 + srow) * LDB + koff + skoff;
    bf16_t* AsD = &u.s.As[wave * 32 * 32];   // half-0 dest for this wave's rows
    bf16_t* BsD = &u.s.Bs[wave * 32 * 32];

    const bf16_t* Ard = &u.s.As[(wm * 64 + col16) * 32 + q * 8];
    const bf16_t* Brd = &u.s.Bs[(wn * 64 + col16) * 32 + q * 8];

    f32x4 acc[4][4];
#pragma unroll
    for (int i = 0; i < 4; ++i)
#pragma unroll
        for (int j = 0; j < 4; ++j)
            acc[i][j] = (f32x4){0.f, 0.f, 0.f, 0.f};

    for (int it = 0; it < K / 64; ++it) {
#pragma unroll
        for (int h = 0; h < 2; ++h) {
#pragma unroll
            for (int j = 0; j < 2; ++j) {
                load16_to_lds(Ag + h * 32 + (long)(j * 16) * LDA,
                              AsD + h * 128 * 32 + j * 16 * 32);
                load16_to_lds(Bg + h * 32 + (long)(j * 16) * LDB,
                              BsD + h * 128 * 32 + j * 16 * 32);
            }
        }
        Ag += 64; Bg += 64;
        __syncthreads();

#pragma unroll
        for (int h = 0; h < 2; ++h) {
            bf16x8_t af[4], bfr[4];
#pragma unroll
            for (int mt = 0; mt < 4; ++mt)
                af[mt] = *(const bf16x8_t*)(Ard + h * 4096 + mt * 16 * 32);
#pragma unroll
            for (int nt = 0; nt < 4; ++nt)
                bfr[nt] = *(const bf16x8_t*)(Brd + h * 4096 + nt * 16 * 32);
#pragma unroll
            for (int mt = 0; mt < 4; ++mt)
#pragma unroll
                for (int nt = 0; nt < 4; ++nt)
                    acc[mt][nt] = __builtin_amdgcn_mfma_f32_16x16x32_bf16(
                        af[mt], bfr[nt], acc[mt][nt], 0, 0, 0);
        }
        __syncthreads();
    }

    if (MODE == 1) {
        float* Cf = (float*)Cout;
#pragma unroll
        for (int nt = 0; nt < 4; ++nt) {
            const int col = colB0 + wn * 64 + nt * 16 + col16;
            const float bv = bias[col];
#pragma unroll
            for (int mt = 0; mt < 4; ++mt) {
                const int row0 = rowA0 + wm * 64 + mt * 16 + q * 4;
#pragma unroll
                for (int i = 0; i < 4; ++i)
                    Cf[(long)(row0 + i) * LDC + col] = acc[mt][nt][i] + bv;
            }
        }
    } else if (MODE == 3) {
        float* Cf = (float*)Cout + (long)blockIdx.x * NT * LDC;
#pragma unroll
        for (int nt = 0; nt < 4; ++nt) {
            const int col = wn * 64 + nt * 16 + col16;
#pragma unroll
            for (int mt = 0; mt < 4; ++mt) {
                const int row0 = rowA0 + wm * 64 + mt * 16 + q * 4;
#pragma unroll
                for (int i = 0; i < 4; ++i)
                    Cf[(long)(row0 + i) * LDC + col] = acc[mt][nt][i];
            }
        }
    } else {
        // MODE 0: bf16 output via LDS repack, coalesced 16B stores
        bf16_t* Cb = (bf16_t*)Cout;
#pragma unroll
        for (int half = 0; half < 2; ++half) {
            if (wm == half) {
#pragma unroll
                for (int nt = 0; nt < 4; ++nt) {
                    const int c = wn * 64 + nt * 16 + col16;
                    const float bv = bias[colB0 + c];
#pragma unroll
                    for (int mt = 0; mt < 4; ++mt) {
                        const int rl = mt * 16 + q * 4;
#pragma unroll
                        for (int i = 0; i < 4; ++i)
                            u.Cs[(rl + i) * 136 + c] =
                                (bf16_t)gelu_fast(acc[mt][nt][i] + bv);
                    }
                }
            }
            __syncthreads();
            {
                const int r  = tid >> 2;
                const int c0 = (tid & 3) * 32;
                const long gbase =
                    (long)(rowA0 + half * 64 + r) * LDC + colB0 + c0;
#pragma unroll
                for (int ch = 0; ch < 4; ++ch) {
                    bf16x8_t v = *(const bf16x8_t*)&u.Cs[r * 136 + c0 + ch * 8];
                    *(bf16x8_t*)&Cb[gbase + ch * 8] = v;
                }
            }
            __syncthreads();
        }
    }
}

// ---------------------------------------------------------------------------
extern "C" void kernel_launch(void* const* d_in, const int* in_sizes, int n_in,
                              void* d_out, int out_size, void* d_ws, size_t ws_size,
                              hipStream_t stream)
{
    const float* x    = (const float*)d_in[0];
    const int*   eidx = (const int*)  d_in[1];
    const float* W1   = (const float*)d_in[2];
    const float* b1   = (const float*)d_in[3];
    const float* A1   = (const float*)d_in[4];
    const float* B1   = (const float*)d_in[5];
    const float* W2   = (const float*)d_in[6];
    const float* b2   = (const float*)d_in[7];
    const float* A2   = (const float*)d_in[8];
    const float* B2   = (const float*)d_in[9];
    float* out = (float*)d_out;

    // workspace carve (bytes), peak 121,634,816:
    //   Xaug2 : [0, 68,157,440)                        live whole pass
    //   Xaug1 : [68,157,440, 85,983,232)               dead after GEMM1
    //   W1aug : [85,983,232, 121,634,816)              dead after GEMM1
    //   A1b   : 104,000,000 +512K   (inside W1aug region, used pre-W1aug-prep)
    //   zp1   : 106,954,752 +8M     (ditto)
    //   W2aug : [68,157,440, 102,236,160)              written after zred2
    //   zp2   : [85,983,232, 102,760,448)              used pre-W2aug-prep
    //   A2b   : 104,857,600 +2M     (outside W2aug, used after GEMM1)
    char* ws = (char*)d_ws;
    bf16_t* Xaug2 = (bf16_t*)(ws);
    bf16_t* Xaug1 = (bf16_t*)(ws + 68157440L);
    bf16_t* W1aug = (bf16_t*)(ws + 85983232L);
    bf16_t* W2aug = (bf16_t*)(ws + 68157440L);
    bf16_t* A1b   = (bf16_t*)(ws + 104000000L);
    bf16_t* A2b   = (bf16_t*)(ws + 104857600L);
    float*  zp1   = (float*) (ws + 106954752L);
    float*  zp2   = (float*) (ws + 85983232L);

    // --- layer 1 ---
    conv_x<<<NT * ND / 8 / 256, 256, 0, stream>>>(x, Xaug1);
    prep_main<<<(NER * ND / 8) / 256, 256, 0, stream>>>(A1, A1b, ND, 8, NER * ND / 8);
    {   // LoRA1 split-K: 4 chunks x K=512
        dim3 g(4, NT / 128);
        gemm_bt<512, NK1, ND, 128, 3, 4><<<g, 256, 0, stream>>>(
            Xaug1, A1b, nullptr, (void*)zp1);
    }
    zred<4, NK1><<<NT * 128 / 256, 256, 0, stream>>>(zp1, eidx, Xaug1 + ND);
    prep_main<<<(NH * ND / 8) / 256, 256, 0, stream>>>(W1, W1aug, NK1, 8, NH * ND / 8);
    prep_lora<<<(NH * NER) / 256, 256, 0, stream>>>(B1, W1aug, NH, ND, NK1, NH * NER);
    {   // GEMM1: y = gelu(Xaug1 @ W1aug^T + b1) -> Xaug2[:, 0:NH] bf16
        dim3 g(NH / 128, NT / 128);
        gemm_bt<NK1, NK1, NK1, NK2, 0, NH / 128><<<g, 256, 0, stream>>>(
            Xaug1, W1aug, b1, (void*)Xaug2);
    }

    // --- layer 2 ---
    prep_main<<<(NER * NH / 8) / 256, 256, 0, stream>>>(A2, A2b, NH, 10, NER * NH / 8);
    {   // LoRA2 split-K: 8 chunks x K=1024
        dim3 g(8, NT / 128);
        gemm_bt<1024, NK2, NH, 128, 3, 8><<<g, 256, 0, stream>>>(
            Xaug2, A2b, nullptr, (void*)zp2);
    }
    zred<8, NK2><<<NT * 128 / 256, 256, 0, stream>>>(zp2, eidx, Xaug2 + NH);
    prep_main<<<(ND * NH / 8) / 256, 256, 0, stream>>>(W2, W2aug, NK2, 10, ND * NH / 8);
    prep_lora<<<(ND * NER) / 256, 256, 0, stream>>>(B2, W2aug, ND, NH, NK2, ND * NER);
    {   // GEMM2: out = Xaug2 @ W2aug^T + b2 (fp32)
        dim3 g(ND / 128, NT / 128);
        gemm_bt<NK2, NK2, NK2, ND, 1, ND / 128><<<g, 256, 0, stream>>>(
            Xaug2, W2aug, b2, (void*)out);
    }
}

// Round 5
// 598.109 us; speedup vs baseline: 1.3024x; 1.0298x over previous
//
#include <hip/hip_runtime.h>
#include <hip/hip_bf16.h>
#include <math.h>

typedef __bf16 bf16_t;
typedef __bf16 bf16x4_t __attribute__((ext_vector_type(4)));
typedef __bf16 bf16x8_t __attribute__((ext_vector_type(8)));
typedef float  f32x4    __attribute__((ext_vector_type(4)));

#define NE  8
#define NR  16
#define ND  2048
#define NH  8192
#define NT  4096
#define NER 128              // NE*NR
#define NK1 (ND + NER)       // 2176
#define NK2 (NH + NER)       // 8320

// gelu_new via sigmoid: 0.5x(1+tanh(u)) == x * sigmoid(2u)
static __device__ __forceinline__ float gelu_fast(float x) {
    const float c2 = 1.5957691216057308f;  // 2*sqrt(2/pi)
    float u2 = c2 * (x + 0.044715f * x * x * x);
    return x / (1.0f + __expf(-u2));
}

static __device__ __forceinline__ void load16_to_lds(const bf16_t* g, bf16_t* l) {
    __builtin_amdgcn_global_load_lds(
        (__attribute__((address_space(1))) void*)(g),
        (__attribute__((address_space(3))) void*)(l),
        16, 0, 0);
}

// ---------------------------------------------------------------------------
// x fp32 -> Xaug1[:, 0:ND] bf16  (8 elems/thread)
// ---------------------------------------------------------------------------
__global__ __launch_bounds__(256) void conv_x(
    const float* __restrict__ x, bf16_t* __restrict__ Xa1)
{
    const int i  = blockIdx.x * 256 + threadIdx.x;   // < NT*ND/8
    const int row = i >> 8;                          // ND/8 = 256
    const int c8  = i & 255;
    f32x4 v0 = *(const f32x4*)(x + (long)i * 8);
    f32x4 v1 = *(const f32x4*)(x + (long)i * 8 + 4);
    bf16x8_t o = {(bf16_t)v0[0], (bf16_t)v0[1], (bf16_t)v0[2], (bf16_t)v0[3],
                  (bf16_t)v1[0], (bf16_t)v1[1], (bf16_t)v1[2], (bf16_t)v1[3]};
    *(bf16x8_t*)(Xa1 + (long)row * NK1 + (c8 << 3)) = o;
}

// fp32 [nrows][K0] -> bf16 [nrows][ld], 8 elems/thread; shift8 = log2(K0/8)
__global__ __launch_bounds__(256) void prep_main(
    const float* __restrict__ W, bf16_t* __restrict__ Waug,
    int ld, int shift8, int total8)
{
    const int i = blockIdx.x * 256 + threadIdx.x;
    if (i >= total8) return;
    const int row = i >> shift8;
    const int c8  = i & ((1 << shift8) - 1);
    f32x4 v0 = *(const f32x4*)(W + (long)i * 8);
    f32x4 v1 = *(const f32x4*)(W + (long)i * 8 + 4);
    bf16x8_t o = {(bf16_t)v0[0], (bf16_t)v0[1], (bf16_t)v0[2], (bf16_t)v0[3],
                  (bf16_t)v1[0], (bf16_t)v1[1], (bf16_t)v1[2], (bf16_t)v1[3]};
    *(bf16x8_t*)(Waug + (long)row * ld + (c8 << 3)) = o;
}

// lora region: Waug[row][K0 + e*16 + r] = Blora[e][row][r]
__global__ __launch_bounds__(256) void prep_lora(
    const float* __restrict__ Bl, bf16_t* __restrict__ Waug,
    int nrows, int K0, int ld, int total)
{
    const int i = blockIdx.x * 256 + threadIdx.x;
    if (i >= total) return;
    const int row = i >> 7;
    const int c   = i & 127;
    const int e   = c >> 4;
    const int r   = c & 15;
    float v = Bl[((long)e * nrows + row) * NR + r];
    Waug[(long)row * ld + K0 + c] = (bf16_t)v;
}

// split-K reduce for LoRA: sum partials, expert-mask, *2, -> bf16 lora cols
template <int SPLITS, int LD>
__global__ __launch_bounds__(256) void zred(
    const float* __restrict__ zp, const int* __restrict__ eidx,
    bf16_t* __restrict__ dst)
{
    const int i = blockIdx.x * 256 + threadIdx.x;  // < NT*128
    const int t = i >> 7;
    const int c = i & 127;
    float s = 0.f;
#pragma unroll
    for (int j = 0; j < SPLITS; ++j) s += zp[(long)j * NT * 128 + i];
    const int e = eidx[t];
    float v = ((c >> 4) == e) ? 2.0f * s : 0.f;
    dst[(long)t * LD + c] = (bf16_t)v;
}

// ---------------------------------------------------------------------------
// bf16 GEMM: C[m][n] = sum_k A[m][k]*Bt[n][k]
// BM x BN tile, W waves (WM x WN), BK=64 staged as two K=32 half-buffers
// (row stride 64 B -> 2-way-free LDS banking), 16x16x32 MFMA,
// global_load_lds width=16. Natural block order (no swizzle).
// MODE 0: +bias, gelu -> bf16 (coalesced via LDS repack)
// MODE 1: +bias -> fp32 direct store
// MODE 3: split-K partial: blockIdx.x = k-chunk, colB0=0, fp32 -> zp[chunk]
// ---------------------------------------------------------------------------
template <int BM, int BN, int W, int WM, int WN,
          int K, int LDA, int LDB, int LDC, int MODE>
__global__ __launch_bounds__(W * 64) void gemm_bt(
    const bf16_t* __restrict__ A,  const bf16_t* __restrict__ Bt,
    const float* __restrict__ bias, void* __restrict__ Cout)
{
    constexpr int RW  = BM / WM;       // rows per wave
    constexpr int CW  = BN / WN;       // cols per wave
    constexpr int MT  = RW / 16;       // m-tiles per wave
    constexpr int NTn = CW / 16;       // n-tiles per wave
    constexpr int AI  = BM / 16 / W;   // A staging instrs per wave per half
    constexpr int BI  = BN / 16 / W;

    __shared__ union {
        struct { bf16_t As[2 * BM * 32]; bf16_t Bs[2 * BN * 32]; } s;
        bf16_t Cs[64 * 264];
    } u;

    const int tid   = threadIdx.x;
    const int wave  = tid >> 6;
    const int lane  = tid & 63;
    const int col16 = lane & 15;
    const int q     = lane >> 4;
    const int wm    = wave % WM;
    const int wn    = wave / WM;

    const int  rowA0 = blockIdx.y * BM;
    const int  colB0 = (MODE == 3) ? 0 : blockIdx.x * BN;
    const long koff  = (MODE == 3) ? (long)blockIdx.x * K : 0;

    // staging: one global_load_lds = 64 lanes x 16B = 16 rows x 32-k (half)
    const int srow  = lane >> 2;        // 0..15
    const int skoff = (lane & 3) * 8;   // k offset within 32-half

    const bf16_t* Agp[AI][2];
    const bf16_t* Bgp[BI][2];
    bf16_t*       AsD[AI][2];
    bf16_t*       BsD[BI][2];
#pragma unroll
    for (int jj = 0; jj < AI; ++jj) {
        const int j = (wave + jj * W) * 16;
#pragma unroll
        for (int h = 0; h < 2; ++h) {
            Agp[jj][h] = A + (long)(rowA0 + j + srow) * LDA + koff + h * 32 + skoff;
            AsD[jj][h] = &u.s.As[(h * BM + j) * 32];
        }
    }
#pragma unroll
    for (int jj = 0; jj < BI; ++jj) {
        const int j = (wave + jj * W) * 16;
#pragma unroll
        for (int h = 0; h < 2; ++h) {
            Bgp[jj][h] = Bt + (long)(colB0 + j + srow) * LDB + koff + h * 32 + skoff;
            BsD[jj][h] = &u.s.Bs[(h * BN + j) * 32];
        }
    }

    const bf16_t* Ard = &u.s.As[(wm * RW + col16) * 32 + q * 8];
    const bf16_t* Brd = &u.s.Bs[(wn * CW + col16) * 32 + q * 8];

    f32x4 acc[MT][NTn];
#pragma unroll
    for (int i = 0; i < MT; ++i)
#pragma unroll
        for (int j = 0; j < NTn; ++j)
            acc[i][j] = (f32x4){0.f, 0.f, 0.f, 0.f};

    for (int it = 0; it < K / 64; ++it) {
#pragma unroll
        for (int jj = 0; jj < AI; ++jj)
#pragma unroll
            for (int h = 0; h < 2; ++h) {
                load16_to_lds(Agp[jj][h], AsD[jj][h]);
                Agp[jj][h] += 64;
            }
#pragma unroll
        for (int jj = 0; jj < BI; ++jj)
#pragma unroll
            for (int h = 0; h < 2; ++h) {
                load16_to_lds(Bgp[jj][h], BsD[jj][h]);
                Bgp[jj][h] += 64;
            }
        __syncthreads();

#pragma unroll
        for (int h = 0; h < 2; ++h) {
            bf16x8_t af[MT], bfr[NTn];
#pragma unroll
            for (int mt = 0; mt < MT; ++mt)
                af[mt] = *(const bf16x8_t*)(Ard + (h * BM + mt * 16) * 32);
#pragma unroll
            for (int nt = 0; nt < NTn; ++nt)
                bfr[nt] = *(const bf16x8_t*)(Brd + (h * BN + nt * 16) * 32);
#pragma unroll
            for (int mt = 0; mt < MT; ++mt)
#pragma unroll
                for (int nt = 0; nt < NTn; ++nt)
                    acc[mt][nt] = __builtin_amdgcn_mfma_f32_16x16x32_bf16(
                        af[mt], bfr[nt], acc[mt][nt], 0, 0, 0);
        }
        __syncthreads();
    }

    if (MODE == 1) {
        float* Cf = (float*)Cout;
#pragma unroll
        for (int nt = 0; nt < NTn; ++nt) {
            const int col = colB0 + wn * CW + nt * 16 + col16;
            const float bv = bias[col];
#pragma unroll
            for (int mt = 0; mt < MT; ++mt) {
                const int row0 = rowA0 + wm * RW + mt * 16 + q * 4;
#pragma unroll
                for (int i = 0; i < 4; ++i)
                    Cf[(long)(row0 + i) * LDC + col] = acc[mt][nt][i] + bv;
            }
        }
    } else if (MODE == 3) {
        float* Cf = (float*)Cout + (long)blockIdx.x * NT * LDC;
#pragma unroll
        for (int nt = 0; nt < NTn; ++nt) {
            const int col = wn * CW + nt * 16 + col16;
#pragma unroll
            for (int mt = 0; mt < MT; ++mt) {
                const int row0 = rowA0 + wm * RW + mt * 16 + q * 4;
#pragma unroll
                for (int i = 0; i < 4; ++i)
                    Cf[(long)(row0 + i) * LDC + col] = acc[mt][nt][i];
            }
        }
    } else {
        // MODE 0: bf16 output via LDS repack, 64-row phases, 16B stores
        bf16_t* Cb = (bf16_t*)Cout;
#pragma unroll
        for (int ph = 0; ph < BM / 64; ++ph) {
            const int phwm = (ph * 64) / RW;           // owning wave-row
            const int mtb  = ((ph * 64) % RW) / 16;    // first m-tile of phase
            if (wm == phwm) {
#pragma unroll
                for (int nt = 0; nt < NTn; ++nt) {
                    const int c = wn * CW + nt * 16 + col16;
                    const float bv = bias[colB0 + c];
#pragma unroll
                    for (int mt = 0; mt < 4; ++mt) {
                        const int rl = mt * 16 + q * 4;
#pragma unroll
                        for (int i = 0; i < 4; ++i)
                            u.Cs[(rl + i) * 264 + c] =
                                (bf16_t)gelu_fast(acc[mtb + mt][nt][i] + bv);
                    }
                }
            }
            __syncthreads();
            {
                constexpr int CPR = BN / 32;           // 32-col chunks per row
                const int r  = tid / CPR;              // 0..63
                const int c0 = (tid % CPR) * 32;
                const long gbase =
                    (long)(rowA0 + ph * 64 + r) * LDC + colB0 + c0;
#pragma unroll
                for (int ch = 0; ch < 4; ++ch) {
                    bf16x8_t v = *(const bf16x8_t*)&u.Cs[r * 264 + c0 + ch * 8];
                    *(bf16x8_t*)&Cb[gbase + ch * 8] = v;
                }
            }
            __syncthreads();
        }
    }
}

// ---------------------------------------------------------------------------
extern "C" void kernel_launch(void* const* d_in, const int* in_sizes, int n_in,
                              void* d_out, int out_size, void* d_ws, size_t ws_size,
                              hipStream_t stream)
{
    const float* x    = (const float*)d_in[0];
    const int*   eidx = (const int*)  d_in[1];
    const float* W1   = (const float*)d_in[2];
    const float* b1   = (const float*)d_in[3];
    const float* A1   = (const float*)d_in[4];
    const float* B1   = (const float*)d_in[5];
    const float* W2   = (const float*)d_in[6];
    const float* b2   = (const float*)d_in[7];
    const float* A2   = (const float*)d_in[8];
    const float* B2   = (const float*)d_in[9];
    float* out = (float*)d_out;

    // workspace carve (bytes), peak 121,634,816:
    //   Xaug2 : [0, 68,157,440)                        live whole pass
    //   Xaug1 : [68,157,440, 85,983,232)               dead after GEMM1
    //   W1aug : [85,983,232, 121,634,816)              dead after GEMM1
    //   A1b   : 104,000,000 +512K   (inside W1aug region, used pre-W1aug-prep)
    //   zp1   : 106,954,752 +8M     (ditto)
    //   W2aug : [68,157,440, 102,236,160)              written after zred2
    //   zp2   : [85,983,232, 102,760,448)              used pre-W2aug-prep
    //   A2b   : 104,857,600 +2M     (outside W2aug, used after GEMM1)
    char* ws = (char*)d_ws;
    bf16_t* Xaug2 = (bf16_t*)(ws);
    bf16_t* Xaug1 = (bf16_t*)(ws + 68157440L);
    bf16_t* W1aug = (bf16_t*)(ws + 85983232L);
    bf16_t* W2aug = (bf16_t*)(ws + 68157440L);
    bf16_t* A1b   = (bf16_t*)(ws + 104000000L);
    bf16_t* A2b   = (bf16_t*)(ws + 104857600L);
    float*  zp1   = (float*) (ws + 106954752L);
    float*  zp2   = (float*) (ws + 85983232L);

    // --- layer 1 ---
    conv_x<<<NT * ND / 8 / 256, 256, 0, stream>>>(x, Xaug1);
    prep_main<<<(NER * ND / 8) / 256, 256, 0, stream>>>(A1, A1b, ND, 8, NER * ND / 8);
    {   // LoRA1 split-K: 4 chunks x K=512
        dim3 g(4, NT / 128);
        gemm_bt<128, 128, 4, 2, 2, 512, NK1, ND, 128, 3><<<g, 256, 0, stream>>>(
            Xaug1, A1b, nullptr, (void*)zp1);
    }
    zred<4, NK1><<<NT * 128 / 256, 256, 0, stream>>>(zp1, eidx, Xaug1 + ND);
    prep_main<<<(NH * ND / 8) / 256, 256, 0, stream>>>(W1, W1aug, NK1, 8, NH * ND / 8);
    prep_lora<<<(NH * NER) / 256, 256, 0, stream>>>(B1, W1aug, NH, ND, NK1, NH * NER);
    {   // GEMM1: y = gelu(Xaug1 @ W1aug^T + b1) -> Xaug2[:, 0:NH] bf16
        //         256x256 tile, 512 threads, 512 blocks
        dim3 g(NH / 256, NT / 256);
        gemm_bt<256, 256, 8, 2, 4, NK1, NK1, NK1, NK2, 0><<<g, 512, 0, stream>>>(
            Xaug1, W1aug, b1, (void*)Xaug2);
    }

    // --- layer 2 ---
    prep_main<<<(NER * NH / 8) / 256, 256, 0, stream>>>(A2, A2b, NH, 10, NER * NH / 8);
    {   // LoRA2 split-K: 8 chunks x K=1024
        dim3 g(8, NT / 128);
        gemm_bt<128, 128, 4, 2, 2, 1024, NK2, NH, 128, 3><<<g, 256, 0, stream>>>(
            Xaug2, A2b, nullptr, (void*)zp2);
    }
    zred<8, NK2><<<NT * 128 / 256, 256, 0, stream>>>(zp2, eidx, Xaug2 + NH);
    prep_main<<<(ND * NH / 8) / 256, 256, 0, stream>>>(W2, W2aug, NK2, 10, ND * NH / 8);
    prep_lora<<<(ND * NER) / 256, 256, 0, stream>>>(B2, W2aug, ND, NH, NK2, ND * NER);
    {   // GEMM2: out = Xaug2 @ W2aug^T + b2 (fp32), 128x128 (control)
        dim3 g(ND / 128, NT / 128);
        gemm_bt<128, 128, 4, 2, 2, NK2, NK2, NK2, ND, 1><<<g, 256, 0, stream>>>(
            Xaug2, W2aug, b2, (void*)out);
    }
}